// Round 2
// baseline (200.748 us; speedup 1.0000x reference)
//
#include <hip/hip_runtime.h>
#include <hip/hip_bf16.h>

typedef __bf16 bf16x8 __attribute__((ext_vector_type(8)));
typedef __bf16 bf16x4 __attribute__((ext_vector_type(4)));
typedef float f32x4 __attribute__((ext_vector_type(4)));

#define KDIM 4096   // K = 128 blocks * 32
#define NDIM 4096   // N = 128 blocks * 32
#define NBJ  128    // output block-columns

// ---------------- prep 0: convert x fp32 -> bf16 -----------------------------
__global__ __launch_bounds__(256) void k_cvt_x(const float* __restrict__ x,
                                               __bf16* __restrict__ xb) {
    int i = blockIdx.x * 256 + threadIdx.x;        // each thread: 8 elements
    float4 u = ((const float4*)x)[2 * i];
    float4 v = ((const float4*)x)[2 * i + 1];
    bf16x8 o;
    o[0] = (__bf16)u.x; o[1] = (__bf16)u.y; o[2] = (__bf16)u.z; o[3] = (__bf16)u.w;
    o[4] = (__bf16)v.x; o[5] = (__bf16)v.y; o[6] = (__bf16)v.z; o[7] = (__bf16)v.w;
    ((bf16x8*)xb)[i] = o;
}

// ---------------- prep 1: transpose+convert each 32x32 w block ---------------
// wT[n][c][k] = (bf16)w[n][k][c]  -> MFMA B-fragment is a contiguous 16B load.
__global__ __launch_bounds__(256) void k_wtrans(const float* __restrict__ w,
                                                __bf16* __restrict__ wT) {
    __shared__ __bf16 tile[32][33];
    int n = blockIdx.x, t = threadIdx.x;           // 256 threads, 4 elems each
    float4 v = ((const float4*)(w + (size_t)n * 1024))[t];
    int e = t * 4, k = e >> 5, c = e & 31;         // consecutive c share k
    tile[k][c + 0] = (__bf16)v.x; tile[k][c + 1] = (__bf16)v.y;
    tile[k][c + 2] = (__bf16)v.z; tile[k][c + 3] = (__bf16)v.w;
    __syncthreads();
    int f = t * 4, cc = f >> 5, kk = f & 31;       // output flat = c*32 + k
    bf16x4 o;
    o[0] = tile[kk + 0][cc]; o[1] = tile[kk + 1][cc];
    o[2] = tile[kk + 2][cc]; o[3] = tile[kk + 3][cc];
    ((bf16x4*)(wT + (size_t)n * 1024))[t] = o;
}

// ---------------- prep 2: build CSC (bucket blocks by column j) --------------
__global__ __launch_bounds__(256) void k_csc(const int* __restrict__ idx_j,
                                             int* __restrict__ colptr,
                                             int* __restrict__ collist, int nnz) {
    __shared__ int cnt[NBJ];
    int t = threadIdx.x;
    for (int i = t; i < NBJ; i += 256) cnt[i] = 0;
    __syncthreads();
    for (int n = t; n < nnz; n += 256) atomicAdd(&cnt[idx_j[n]], 1);
    __syncthreads();
    if (t == 0) {
        int run = 0;
        for (int j = 0; j < NBJ; ++j) { int c = cnt[j]; colptr[j] = run; cnt[j] = run; run += c; }
        colptr[NBJ] = run;
    }
    __syncthreads();
    for (int n = t; n < nnz; n += 256) {
        int j = idx_j[n];
        int pos = atomicAdd(&cnt[j], 1);           // cnt now holds cursors
        collist[pos] = n;                          // order within column irrelevant (sum)
    }
}

// ---------------- main kernel (fast path) ------------------------------------
// Grid: (M/256, 128). 4 waves/WG; wave owns 64 rows (4 chunks of 16) x 32 cols.
// Per nonzero block: 8x mfma_f32_16x16x32_bf16 (full K=32 per MFMA).
__global__ __launch_bounds__(256) void k_bsmm(
    const __bf16* __restrict__ x, const __bf16* __restrict__ wT,
    const int* __restrict__ colptr, const int* __restrict__ collist,
    const int* __restrict__ idx_i, float* __restrict__ y) {
    int j    = blockIdx.y;
    int lane = threadIdx.x & 63, wave = threadIdx.x >> 6;
    int quad = lane >> 4, l16 = lane & 15;
    int wrow = blockIdx.x * 256 + wave * 64;

    f32x4 acc[4][2] = {};                          // [row chunk][col half]

    int beg = colptr[j], end = colptr[j + 1];
    for (int p = beg; p < end; ++p) {
        int n  = collist[p];
        int ib = idx_i[n];
        // A fragment: A[m=lane&15][k=quad*8+jj] -> 16B contiguous per lane
        const __bf16* xp = x + (size_t)(wrow + l16) * KDIM + ib * 32 + quad * 8;
        bf16x8 a0 = *(const bf16x8*)(xp);
        bf16x8 a1 = *(const bf16x8*)(xp + 16 * KDIM);
        bf16x8 a2 = *(const bf16x8*)(xp + 32 * KDIM);
        bf16x8 a3 = *(const bf16x8*)(xp + 48 * KDIM);
        // B fragment: B[k=quad*8+jj][n=lane&15] = wT[c][k] -> 16B contiguous
        const __bf16* wp = wT + (size_t)n * 1024 + l16 * 32 + quad * 8;
        bf16x8 b0 = *(const bf16x8*)(wp);          // cols 0..15
        bf16x8 b1 = *(const bf16x8*)(wp + 512);    // cols 16..31
        acc[0][0] = __builtin_amdgcn_mfma_f32_16x16x32_bf16(a0, b0, acc[0][0], 0, 0, 0);
        acc[0][1] = __builtin_amdgcn_mfma_f32_16x16x32_bf16(a0, b1, acc[0][1], 0, 0, 0);
        acc[1][0] = __builtin_amdgcn_mfma_f32_16x16x32_bf16(a1, b0, acc[1][0], 0, 0, 0);
        acc[1][1] = __builtin_amdgcn_mfma_f32_16x16x32_bf16(a1, b1, acc[1][1], 0, 0, 0);
        acc[2][0] = __builtin_amdgcn_mfma_f32_16x16x32_bf16(a2, b0, acc[2][0], 0, 0, 0);
        acc[2][1] = __builtin_amdgcn_mfma_f32_16x16x32_bf16(a2, b1, acc[2][1], 0, 0, 0);
        acc[3][0] = __builtin_amdgcn_mfma_f32_16x16x32_bf16(a3, b0, acc[3][0], 0, 0, 0);
        acc[3][1] = __builtin_amdgcn_mfma_f32_16x16x32_bf16(a3, b1, acc[3][1], 0, 0, 0);
    }

    // C/D layout: row = quad*4 + reg, col = lane&15 (verified m89/m91)
    #pragma unroll
    for (int r = 0; r < 4; ++r)
        #pragma unroll
        for (int ch = 0; ch < 2; ++ch)
            #pragma unroll
            for (int reg = 0; reg < 4; ++reg) {
                int row = wrow + r * 16 + quad * 4 + reg;
                int col = j * 32 + ch * 16 + l16;
                y[(size_t)row * NDIM + col] = acc[r][ch][reg];
            }
}

// ---------------- fallback (no workspace): fp32 reads, convert in-kernel -----
__global__ __launch_bounds__(256) void k_bsmm_nows(
    const float* __restrict__ x, const float* __restrict__ w,
    const int* __restrict__ idx_i, const int* __restrict__ idx_j,
    float* __restrict__ y, int nnz) {
    __shared__ int list[256];
    __shared__ int listn;
    __shared__ __bf16 tw[32][40];   // [c][k], stride 40 bf16 = 80B (16B aligned)
    int j    = blockIdx.y;
    int tid  = threadIdx.x;
    int lane = tid & 63;
    int wave = tid >> 6;
    int quad = lane >> 4, l16 = lane & 15;
    int wrow = blockIdx.x * 256 + wave * 64;

    if (tid == 0) listn = 0;
    __syncthreads();
    for (int n = tid; n < nnz; n += 256)
        if (idx_j[n] == j) { int p = atomicAdd(&listn, 1); list[p & 255] = n; }
    __syncthreads();
    int cnt = listn;

    f32x4 acc[4][2] = {};
    for (int p = 0; p < cnt; ++p) {
        int n  = list[p];
        int ib = idx_i[n];
        {   // stage w[n] transposed+converted into LDS
            float4 v = ((const float4*)(w + (size_t)n * 1024))[tid];
            int e = tid * 4, k = e >> 5, c = e & 31;
            tw[c + 0][k] = (__bf16)v.x; tw[c + 1][k] = (__bf16)v.y;
            tw[c + 2][k] = (__bf16)v.z; tw[c + 3][k] = (__bf16)v.w;
        }
        __syncthreads();
        bf16x8 a[4];
        #pragma unroll
        for (int r = 0; r < 4; ++r) {
            const float* xp = x + (size_t)(wrow + r * 16 + l16) * KDIM + ib * 32 + quad * 8;
            float4 u = *(const float4*)(xp);
            float4 v = *(const float4*)(xp + 4);
            a[r][0] = (__bf16)u.x; a[r][1] = (__bf16)u.y; a[r][2] = (__bf16)u.z; a[r][3] = (__bf16)u.w;
            a[r][4] = (__bf16)v.x; a[r][5] = (__bf16)v.y; a[r][6] = (__bf16)v.z; a[r][7] = (__bf16)v.w;
        }
        bf16x8 b0 = *(const bf16x8*)&tw[l16][quad * 8];
        bf16x8 b1 = *(const bf16x8*)&tw[l16 + 16][quad * 8];
        #pragma unroll
        for (int r = 0; r < 4; ++r) {
            acc[r][0] = __builtin_amdgcn_mfma_f32_16x16x32_bf16(a[r], b0, acc[r][0], 0, 0, 0);
            acc[r][1] = __builtin_amdgcn_mfma_f32_16x16x32_bf16(a[r], b1, acc[r][1], 0, 0, 0);
        }
        __syncthreads();
    }

    #pragma unroll
    for (int r = 0; r < 4; ++r)
        #pragma unroll
        for (int ch = 0; ch < 2; ++ch)
            #pragma unroll
            for (int reg = 0; reg < 4; ++reg) {
                int row = wrow + r * 16 + quad * 4 + reg;
                int col = j * 32 + ch * 16 + l16;
                y[(size_t)row * NDIM + col] = acc[r][ch][reg];
            }
}

extern "C" void kernel_launch(void* const* d_in, const int* in_sizes, int n_in,
                              void* d_out, int out_size, void* d_ws, size_t ws_size,
                              hipStream_t stream) {
    const float* x     = (const float*)d_in[0];
    const float* w     = (const float*)d_in[1];
    const int*   idx_i = (const int*)d_in[2];
    const int*   idx_j = (const int*)d_in[3];
    float*       y     = (float*)d_out;

    int nnz = in_sizes[2];
    int M   = in_sizes[0] / KDIM;                   // 4096
    dim3 grid(M / 256, NBJ);

    size_t xb_bytes = (size_t)M * KDIM * 2;         // 32 MB bf16 x
    size_t wt_bytes = (size_t)nnz * 1024 * 2;       // bf16 wT
    size_t need = xb_bytes + wt_bytes + (size_t)(NBJ + 1 + 3) * 4 + (size_t)nnz * 4;

    if (ws_size >= need) {
        __bf16* xb      = (__bf16*)d_ws;
        __bf16* wT      = (__bf16*)((char*)d_ws + xb_bytes);
        int*    colptr  = (int*)((char*)d_ws + xb_bytes + wt_bytes);
        int*    collist = colptr + NBJ + 1 + 3;
        int nx = (M * KDIM) / 8 / 256;              // 8192 blocks
        k_cvt_x<<<nx, 256, 0, stream>>>(x, xb);
        k_wtrans<<<nnz, 256, 0, stream>>>(w, wT);
        k_csc<<<1, 256, 0, stream>>>(idx_j, colptr, collist, nnz);
        k_bsmm<<<grid, 256, 0, stream>>>(xb, wT, colptr, collist, idx_i, y);
    } else {
        k_bsmm_nows<<<grid, 256, 0, stream>>>(x, w, idx_i, idx_j, y, nnz);
    }
}

// Round 3
// 197.401 us; speedup vs baseline: 1.0170x; 1.0170x over previous
//
#include <hip/hip_runtime.h>
#include <hip/hip_bf16.h>

typedef __bf16 bf16x8 __attribute__((ext_vector_type(8)));
typedef __bf16 bf16x4 __attribute__((ext_vector_type(4)));
typedef float f32x4 __attribute__((ext_vector_type(4)));

#define KDIM 4096   // K = 128 blocks * 32
#define NDIM 4096   // N = 128 blocks * 32
#define NBJ  128    // output block-columns
#define KB   128    // input  block-rows

// ---- prep 0: convert + PERMUTE x: xb2[i][m][k] = bf16(x[m][i*32+k]) ---------
// Block-column-major so MFMA A-fragments are contiguous 1KB/wave loads.
__global__ __launch_bounds__(256) void k_cvt_x(const float* __restrict__ x,
                                               __bf16* __restrict__ xb, int M) {
    int i  = blockIdx.x;                 // k-block index
    int m0 = blockIdx.y * 64;            // row group
    int q  = threadIdx.x & 3, r = threadIdx.x >> 2;   // q: 8-elem quarter, r: row
    const float* xp = x + (size_t)(m0 + r) * KDIM + i * 32 + q * 8;
    float4 u = ((const float4*)xp)[0];
    float4 v = ((const float4*)xp)[1];
    bf16x8 o;
    o[0]=(__bf16)u.x; o[1]=(__bf16)u.y; o[2]=(__bf16)u.z; o[3]=(__bf16)u.w;
    o[4]=(__bf16)v.x; o[5]=(__bf16)v.y; o[6]=(__bf16)v.z; o[7]=(__bf16)v.w;
    *(bf16x8*)(xb + ((size_t)i * M + m0 + r) * 32 + q * 8) = o;   // contiguous 4KB/wave
}

// ---- prep 1: transpose+convert each 32x32 w block ---------------------------
// wT[n][c][k] = (bf16)w[n][k][c]
__global__ __launch_bounds__(256) void k_wtrans(const float* __restrict__ w,
                                                __bf16* __restrict__ wT) {
    __shared__ __bf16 tile[32][33];
    int n = blockIdx.x, t = threadIdx.x;
    float4 v = ((const float4*)(w + (size_t)n * 1024))[t];
    int e = t * 4, k = e >> 5, c = e & 31;
    tile[k][c + 0] = (__bf16)v.x; tile[k][c + 1] = (__bf16)v.y;
    tile[k][c + 2] = (__bf16)v.z; tile[k][c + 3] = (__bf16)v.w;
    __syncthreads();
    int f = t * 4, cc = f >> 5, kk = f & 31;
    bf16x4 o;
    o[0] = tile[kk + 0][cc]; o[1] = tile[kk + 1][cc];
    o[2] = tile[kk + 2][cc]; o[3] = tile[kk + 3][cc];
    ((bf16x4*)(wT + (size_t)n * 1024))[t] = o;
}

// ---- prep 2: CSC with packed (ib<<16)|n, parallel scan ----------------------
__global__ __launch_bounds__(256) void k_csc(const int* __restrict__ idx_i,
                                             const int* __restrict__ idx_j,
                                             int* __restrict__ colptr,
                                             int* __restrict__ colinfo, int nnz) {
    __shared__ int cnt[NBJ], cur[NBJ];
    int t = threadIdx.x;
    if (t < NBJ) cnt[t] = 0;
    __syncthreads();
    for (int n = t; n < nnz; n += 256) atomicAdd(&cnt[idx_j[n]], 1);
    __syncthreads();
    int mycount = (t < NBJ) ? cnt[t] : 0;
    // Hillis-Steele inclusive scan over 128 entries
    for (int off = 1; off < NBJ; off <<= 1) {
        int add = (t < NBJ && t >= off) ? cnt[t - off] : 0;
        __syncthreads();
        if (t < NBJ) cnt[t] += add;
        __syncthreads();
    }
    if (t < NBJ) {
        colptr[t + 1] = cnt[t];
        cur[t] = cnt[t] - mycount;      // exclusive start = cursor
        if (t == 0) colptr[0] = 0;
    }
    __syncthreads();
    for (int n = t; n < nnz; n += 256) {
        int j = idx_j[n];
        int pos = atomicAdd(&cur[j], 1);
        colinfo[pos] = (idx_i[n] << 16) | n;   // order in column irrelevant
    }
}

// ---- main kernel ------------------------------------------------------------
// 1-D grid, decoded so all row-WGs of column j share xcd = linear%8 (L2 reuse).
// No LDS, no barriers, no index loads in the loop (shfl broadcast), 1-deep
// load pipeline: next block's 6 loads in flight during current 8 MFMAs.
struct Frag { bf16x8 a0, a1, a2, a3, b0, b1; };

__global__ __launch_bounds__(256) void k_bsmm(
    const __bf16* __restrict__ xb, const __bf16* __restrict__ wT,
    const int* __restrict__ colptr, const int* __restrict__ colinfo,
    float* __restrict__ y, int M) {
    int RCH = M >> 8;                         // row-chunks of 256 (16 for M=4096)
    int l = blockIdx.x;
    int s = l & 7, t = l >> 3;
    int j = (t / RCH) * 8 + s;                // column block: same-j WGs -> same XCD slot
    int rc = t % RCH;                         // row chunk
    int lane = threadIdx.x & 63, wave = threadIdx.x >> 6;
    int quad = lane >> 4, l16 = lane & 15;
    int wrow = rc * 256 + wave * 64;

    int beg = colptr[j], end = colptr[j + 1];
    int cnt = end - beg;

    f32x4 acc[4][2] = {};

    if (cnt > 0) {
        // preload up to 64 column entries, one per lane
        int einfo = colinfo[beg + (lane < cnt ? lane : cnt - 1)];

        auto fetch = [&](int p) {
            int ee = (p < 64) ? __shfl(einfo, p) : colinfo[beg + p];
            int n = ee & 0xFFFF, ib = ee >> 16;
            Frag f;
            const __bf16* xp = xb + ((size_t)ib * M + wrow + l16) * 32 + quad * 8;
            f.a0 = *(const bf16x8*)(xp);
            f.a1 = *(const bf16x8*)(xp + 16 * 32);
            f.a2 = *(const bf16x8*)(xp + 32 * 32);
            f.a3 = *(const bf16x8*)(xp + 48 * 32);
            const __bf16* wp = wT + (size_t)n * 1024 + l16 * 32 + quad * 8;
            f.b0 = *(const bf16x8*)(wp);
            f.b1 = *(const bf16x8*)(wp + 512);
            return f;
        };

        Frag c = fetch(0);
        for (int p = 0; p < cnt; ++p) {
            Frag nx = c;
            if (p + 1 < cnt) nx = fetch(p + 1);
            acc[0][0] = __builtin_amdgcn_mfma_f32_16x16x32_bf16(c.a0, c.b0, acc[0][0], 0, 0, 0);
            acc[0][1] = __builtin_amdgcn_mfma_f32_16x16x32_bf16(c.a0, c.b1, acc[0][1], 0, 0, 0);
            acc[1][0] = __builtin_amdgcn_mfma_f32_16x16x32_bf16(c.a1, c.b0, acc[1][0], 0, 0, 0);
            acc[1][1] = __builtin_amdgcn_mfma_f32_16x16x32_bf16(c.a1, c.b1, acc[1][1], 0, 0, 0);
            acc[2][0] = __builtin_amdgcn_mfma_f32_16x16x32_bf16(c.a2, c.b0, acc[2][0], 0, 0, 0);
            acc[2][1] = __builtin_amdgcn_mfma_f32_16x16x32_bf16(c.a2, c.b1, acc[2][1], 0, 0, 0);
            acc[3][0] = __builtin_amdgcn_mfma_f32_16x16x32_bf16(c.a3, c.b0, acc[3][0], 0, 0, 0);
            acc[3][1] = __builtin_amdgcn_mfma_f32_16x16x32_bf16(c.a3, c.b1, acc[3][1], 0, 0, 0);
            c = nx;
        }
    }

    // C/D layout: row = quad*4 + reg, col = lane&15
    #pragma unroll
    for (int r = 0; r < 4; ++r)
        #pragma unroll
        for (int ch = 0; ch < 2; ++ch)
            #pragma unroll
            for (int reg = 0; reg < 4; ++reg) {
                int row = wrow + r * 16 + quad * 4 + reg;
                int col = j * 32 + ch * 16 + l16;
                y[(size_t)row * NDIM + col] = acc[r][ch][reg];
            }
}

// ---- fallback (no workspace): fp32 reads, convert in-kernel -----------------
__global__ __launch_bounds__(256) void k_bsmm_nows(
    const float* __restrict__ x, const float* __restrict__ w,
    const int* __restrict__ idx_i, const int* __restrict__ idx_j,
    float* __restrict__ y, int nnz) {
    __shared__ int list[256];
    __shared__ int listn;
    __shared__ __bf16 tw[32][40];
    int j = blockIdx.y;
    int tid = threadIdx.x;
    int lane = tid & 63, wave = tid >> 6;
    int quad = lane >> 4, l16 = lane & 15;
    int wrow = blockIdx.x * 256 + wave * 64;

    if (tid == 0) listn = 0;
    __syncthreads();
    for (int n = tid; n < nnz; n += 256)
        if (idx_j[n] == j) { int p = atomicAdd(&listn, 1); list[p & 255] = n; }
    __syncthreads();
    int cnt = listn;

    f32x4 acc[4][2] = {};
    for (int p = 0; p < cnt; ++p) {
        int n = list[p];
        int ib = idx_i[n];
        {
            float4 v = ((const float4*)(w + (size_t)n * 1024))[tid];
            int e = tid * 4, k = e >> 5, c = e & 31;
            tw[c + 0][k] = (__bf16)v.x; tw[c + 1][k] = (__bf16)v.y;
            tw[c + 2][k] = (__bf16)v.z; tw[c + 3][k] = (__bf16)v.w;
        }
        __syncthreads();
        bf16x8 a[4];
        #pragma unroll
        for (int r = 0; r < 4; ++r) {
            const float* xp = x + (size_t)(wrow + r * 16 + l16) * KDIM + ib * 32 + quad * 8;
            float4 u = *(const float4*)(xp);
            float4 v = *(const float4*)(xp + 4);
            a[r][0] = (__bf16)u.x; a[r][1] = (__bf16)u.y; a[r][2] = (__bf16)u.z; a[r][3] = (__bf16)u.w;
            a[r][4] = (__bf16)v.x; a[r][5] = (__bf16)v.y; a[r][6] = (__bf16)v.z; a[r][7] = (__bf16)v.w;
        }
        bf16x8 b0 = *(const bf16x8*)&tw[l16][quad * 8];
        bf16x8 b1 = *(const bf16x8*)&tw[l16 + 16][quad * 8];
        #pragma unroll
        for (int r = 0; r < 4; ++r) {
            acc[r][0] = __builtin_amdgcn_mfma_f32_16x16x32_bf16(a[r], b0, acc[r][0], 0, 0, 0);
            acc[r][1] = __builtin_amdgcn_mfma_f32_16x16x32_bf16(a[r], b1, acc[r][1], 0, 0, 0);
        }
        __syncthreads();
    }

    #pragma unroll
    for (int r = 0; r < 4; ++r)
        #pragma unroll
        for (int ch = 0; ch < 2; ++ch)
            #pragma unroll
            for (int reg = 0; reg < 4; ++reg) {
                int row = wrow + r * 16 + quad * 4 + reg;
                int col = j * 32 + ch * 16 + l16;
                y[(size_t)row * NDIM + col] = acc[r][ch][reg];
            }
}

extern "C" void kernel_launch(void* const* d_in, const int* in_sizes, int n_in,
                              void* d_out, int out_size, void* d_ws, size_t ws_size,
                              hipStream_t stream) {
    const float* x     = (const float*)d_in[0];
    const float* w     = (const float*)d_in[1];
    const int*   idx_i = (const int*)d_in[2];
    const int*   idx_j = (const int*)d_in[3];
    float*       y     = (float*)d_out;

    int nnz = in_sizes[2];
    int M   = in_sizes[0] / KDIM;                   // 4096

    size_t xb_bytes = (size_t)M * KDIM * 2;         // 32 MB
    size_t wt_bytes = (size_t)nnz * 1024 * 2;
    size_t need = xb_bytes + wt_bytes + (size_t)(NBJ + 2 + nnz) * 4;

    if (ws_size >= need && (M & 255) == 0) {
        __bf16* xb      = (__bf16*)d_ws;
        __bf16* wT      = (__bf16*)((char*)d_ws + xb_bytes);
        int*    colptr  = (int*)((char*)d_ws + xb_bytes + wt_bytes);
        int*    colinfo = colptr + NBJ + 1;
        k_cvt_x<<<dim3(KB, M / 64), 256, 0, stream>>>(x, xb, M);
        k_wtrans<<<nnz, 256, 0, stream>>>(w, wT);
        k_csc<<<1, 256, 0, stream>>>(idx_i, idx_j, colptr, colinfo, nnz);
        k_bsmm<<<(M / 256) * NBJ, 256, 0, stream>>>(xb, wT, colptr, colinfo, y, M);
    } else {
        k_bsmm_nows<<<dim3(M / 256, NBJ), 256, 0, stream>>>(x, w, idx_i, idx_j, y, nnz);
    }
}

// Round 4
// 179.979 us; speedup vs baseline: 1.1154x; 1.0968x over previous
//
#include <hip/hip_runtime.h>
#include <hip/hip_bf16.h>

typedef __bf16 bf16x8 __attribute__((ext_vector_type(8)));
typedef __bf16 bf16x4 __attribute__((ext_vector_type(4)));
typedef float f32x4 __attribute__((ext_vector_type(4)));

#define KDIM 4096   // K = 128 blocks * 32
#define NDIM 4096   // N = 128 blocks * 32
#define NBJ  128    // output block-columns
#define KB   128    // input  block-rows

// ---- prep 0: convert + PERMUTE x: xb[i][m][k] = bf16(x[m][i*32+k]) ----------
__global__ __launch_bounds__(256) void k_cvt_x(const float* __restrict__ x,
                                               __bf16* __restrict__ xb, int M) {
    int i  = blockIdx.x;                 // k-block index
    int m0 = blockIdx.y * 64;            // row group
    int q  = threadIdx.x & 3, r = threadIdx.x >> 2;   // q: 8-elem quarter, r: row
    const float* xp = x + (size_t)(m0 + r) * KDIM + i * 32 + q * 8;
    float4 u = ((const float4*)xp)[0];
    float4 v = ((const float4*)xp)[1];
    bf16x8 o;
    o[0]=(__bf16)u.x; o[1]=(__bf16)u.y; o[2]=(__bf16)u.z; o[3]=(__bf16)u.w;
    o[4]=(__bf16)v.x; o[5]=(__bf16)v.y; o[6]=(__bf16)v.z; o[7]=(__bf16)v.w;
    *(bf16x8*)(xb + ((size_t)i * M + m0 + r) * 32 + q * 8) = o;
}

// ---- prep 1: transpose+convert each 32x32 w block: wT[n][c][k]=bf16(w[n][k][c])
__global__ __launch_bounds__(256) void k_wtrans(const float* __restrict__ w,
                                                __bf16* __restrict__ wT) {
    __shared__ __bf16 tile[32][33];
    int n = blockIdx.x, t = threadIdx.x;
    float4 v = ((const float4*)(w + (size_t)n * 1024))[t];
    int e = t * 4, k = e >> 5, c = e & 31;
    tile[k][c + 0] = (__bf16)v.x; tile[k][c + 1] = (__bf16)v.y;
    tile[k][c + 2] = (__bf16)v.z; tile[k][c + 3] = (__bf16)v.w;
    __syncthreads();
    int f = t * 4, cc = f >> 5, kk = f & 31;
    bf16x4 o;
    o[0] = tile[kk + 0][cc]; o[1] = tile[kk + 1][cc];
    o[2] = tile[kk + 2][cc]; o[3] = tile[kk + 3][cc];
    ((bf16x4*)(wT + (size_t)n * 1024))[t] = o;
}

// ---- prep 2: CSC with packed (ib<<16)|n, parallel scan ----------------------
__global__ __launch_bounds__(256) void k_csc(const int* __restrict__ idx_i,
                                             const int* __restrict__ idx_j,
                                             int* __restrict__ colptr,
                                             int* __restrict__ colinfo, int nnz) {
    __shared__ int cnt[NBJ], cur[NBJ];
    int t = threadIdx.x;
    if (t < NBJ) cnt[t] = 0;
    __syncthreads();
    for (int n = t; n < nnz; n += 256) atomicAdd(&cnt[idx_j[n]], 1);
    __syncthreads();
    int mycount = (t < NBJ) ? cnt[t] : 0;
    for (int off = 1; off < NBJ; off <<= 1) {
        int add = (t < NBJ && t >= off) ? cnt[t - off] : 0;
        __syncthreads();
        if (t < NBJ) cnt[t] += add;
        __syncthreads();
    }
    if (t < NBJ) {
        colptr[t + 1] = cnt[t];
        cur[t] = cnt[t] - mycount;
        if (t == 0) colptr[0] = 0;
    }
    __syncthreads();
    for (int n = t; n < nnz; n += 256) {
        int j = idx_j[n];
        int pos = atomicAdd(&cur[j], 1);
        colinfo[pos] = (idx_i[n] << 16) | n;
    }
}

// ---- main kernel ------------------------------------------------------------
// 1-D grid decoded so ALL columns of a row-chunk share an XCD slot (linear%8):
// the rc's 2MB bf16 x-window is reused from that XCD's L2 across 128 columns.
struct Frag { bf16x8 a0, a1, a2, a3, b0, b1; };

__global__ __launch_bounds__(256) void k_bsmm(
    const __bf16* __restrict__ xb, const __bf16* __restrict__ wT,
    const int* __restrict__ colptr, const int* __restrict__ colinfo,
    float* __restrict__ y, int M) {
    int RCH = M >> 8;                          // row-chunks of 256
    int l = blockIdx.x;
    int rc, j;
    if ((RCH & 7) == 0) {                      // XCD swizzle: rc -> slot l&7
        int rps = RCH >> 3;                    // row-chunks per XCD slot
        int s = l & 7, u = l >> 3;
        rc = s * rps + (u % rps);
        j  = u / rps;
    } else {
        rc = l % RCH; j = l / RCH;
    }
    int lane = threadIdx.x & 63, wave = threadIdx.x >> 6;
    int quad = lane >> 4, l16 = lane & 15;
    int wrow = rc * 256 + wave * 64;

    int beg = colptr[j], end = colptr[j + 1];
    int cnt = end - beg;

    f32x4 acc[4][2] = {};

    if (cnt > 0) {
        // preload up to 64 column entries, one per lane; broadcast via shfl
        int einfo = colinfo[beg + (lane < cnt ? lane : cnt - 1)];

        auto fetch = [&](int p) {
            int ee = (p < 64) ? __shfl(einfo, p) : colinfo[beg + p];
            int n = ee & 0xFFFF, ib = ee >> 16;
            Frag f;
            const __bf16* xp = xb + ((size_t)ib * M + wrow + l16) * 32 + quad * 8;
            f.a0 = *(const bf16x8*)(xp);
            f.a1 = *(const bf16x8*)(xp + 16 * 32);
            f.a2 = *(const bf16x8*)(xp + 32 * 32);
            f.a3 = *(const bf16x8*)(xp + 48 * 32);
            const __bf16* wp = wT + (size_t)n * 1024 + l16 * 32 + quad * 8;
            f.b0 = *(const bf16x8*)(wp);
            f.b1 = *(const bf16x8*)(wp + 512);
            return f;
        };

        Frag c = fetch(0);
        for (int p = 0; p < cnt; ++p) {
            Frag nx = c;
            if (p + 1 < cnt) nx = fetch(p + 1);
            acc[0][0] = __builtin_amdgcn_mfma_f32_16x16x32_bf16(c.a0, c.b0, acc[0][0], 0, 0, 0);
            acc[0][1] = __builtin_amdgcn_mfma_f32_16x16x32_bf16(c.a0, c.b1, acc[0][1], 0, 0, 0);
            acc[1][0] = __builtin_amdgcn_mfma_f32_16x16x32_bf16(c.a1, c.b0, acc[1][0], 0, 0, 0);
            acc[1][1] = __builtin_amdgcn_mfma_f32_16x16x32_bf16(c.a1, c.b1, acc[1][1], 0, 0, 0);
            acc[2][0] = __builtin_amdgcn_mfma_f32_16x16x32_bf16(c.a2, c.b0, acc[2][0], 0, 0, 0);
            acc[2][1] = __builtin_amdgcn_mfma_f32_16x16x32_bf16(c.a2, c.b1, acc[2][1], 0, 0, 0);
            acc[3][0] = __builtin_amdgcn_mfma_f32_16x16x32_bf16(c.a3, c.b0, acc[3][0], 0, 0, 0);
            acc[3][1] = __builtin_amdgcn_mfma_f32_16x16x32_bf16(c.a3, c.b1, acc[3][1], 0, 0, 0);
            c = nx;
        }
    }

    // C/D layout: row = quad*4 + reg, col = lane&15
    #pragma unroll
    for (int r = 0; r < 4; ++r)
        #pragma unroll
        for (int ch = 0; ch < 2; ++ch)
            #pragma unroll
            for (int reg = 0; reg < 4; ++reg) {
                int row = wrow + r * 16 + quad * 4 + reg;
                int col = j * 32 + ch * 16 + l16;
                y[(size_t)row * NDIM + col] = acc[r][ch][reg];
            }
}

// ---- fallback (no workspace): fp32 reads, convert in-kernel -----------------
__global__ __launch_bounds__(256) void k_bsmm_nows(
    const float* __restrict__ x, const float* __restrict__ w,
    const int* __restrict__ idx_i, const int* __restrict__ idx_j,
    float* __restrict__ y, int nnz) {
    __shared__ int list[256];
    __shared__ int listn;
    __shared__ __bf16 tw[32][40];
    int j = blockIdx.y;
    int tid = threadIdx.x;
    int lane = tid & 63, wave = tid >> 6;
    int quad = lane >> 4, l16 = lane & 15;
    int wrow = blockIdx.x * 256 + wave * 64;

    if (tid == 0) listn = 0;
    __syncthreads();
    for (int n = tid; n < nnz; n += 256)
        if (idx_j[n] == j) { int p = atomicAdd(&listn, 1); list[p & 255] = n; }
    __syncthreads();
    int cnt = listn;

    f32x4 acc[4][2] = {};
    for (int p = 0; p < cnt; ++p) {
        int n = list[p];
        int ib = idx_i[n];
        {
            float4 v = ((const float4*)(w + (size_t)n * 1024))[tid];
            int e = tid * 4, k = e >> 5, c = e & 31;
            tw[c + 0][k] = (__bf16)v.x; tw[c + 1][k] = (__bf16)v.y;
            tw[c + 2][k] = (__bf16)v.z; tw[c + 3][k] = (__bf16)v.w;
        }
        __syncthreads();
        bf16x8 a[4];
        #pragma unroll
        for (int r = 0; r < 4; ++r) {
            const float* xp = x + (size_t)(wrow + r * 16 + l16) * KDIM + ib * 32 + quad * 8;
            float4 u = *(const float4*)(xp);
            float4 v = *(const float4*)(xp + 4);
            a[r][0] = (__bf16)u.x; a[r][1] = (__bf16)u.y; a[r][2] = (__bf16)u.z; a[r][3] = (__bf16)u.w;
            a[r][4] = (__bf16)v.x; a[r][5] = (__bf16)v.y; a[r][6] = (__bf16)v.z; a[r][7] = (__bf16)v.w;
        }
        bf16x8 b0 = *(const bf16x8*)&tw[l16][quad * 8];
        bf16x8 b1 = *(const bf16x8*)&tw[l16 + 16][quad * 8];
        #pragma unroll
        for (int r = 0; r < 4; ++r) {
            acc[r][0] = __builtin_amdgcn_mfma_f32_16x16x32_bf16(a[r], b0, acc[r][0], 0, 0, 0);
            acc[r][1] = __builtin_amdgcn_mfma_f32_16x16x32_bf16(a[r], b1, acc[r][1], 0, 0, 0);
        }
        __syncthreads();
    }

    #pragma unroll
    for (int r = 0; r < 4; ++r)
        #pragma unroll
        for (int ch = 0; ch < 2; ++ch)
            #pragma unroll
            for (int reg = 0; reg < 4; ++reg) {
                int row = wrow + r * 16 + quad * 4 + reg;
                int col = j * 32 + ch * 16 + l16;
                y[(size_t)row * NDIM + col] = acc[r][ch][reg];
            }
}

extern "C" void kernel_launch(void* const* d_in, const int* in_sizes, int n_in,
                              void* d_out, int out_size, void* d_ws, size_t ws_size,
                              hipStream_t stream) {
    const float* x     = (const float*)d_in[0];
    const float* w     = (const float*)d_in[1];
    const int*   idx_i = (const int*)d_in[2];
    const int*   idx_j = (const int*)d_in[3];
    float*       y     = (float*)d_out;

    int nnz = in_sizes[2];
    int M   = in_sizes[0] / KDIM;                   // 4096

    size_t xb_bytes = (size_t)M * KDIM * 2;         // 32 MB
    size_t wt_bytes = (size_t)nnz * 1024 * 2;
    size_t need = xb_bytes + wt_bytes + (size_t)(NBJ + 2 + nnz) * 4;

    if (ws_size >= need && (M & 255) == 0) {
        __bf16* xb      = (__bf16*)d_ws;
        __bf16* wT      = (__bf16*)((char*)d_ws + xb_bytes);
        int*    colptr  = (int*)((char*)d_ws + xb_bytes + wt_bytes);
        int*    colinfo = colptr + NBJ + 1;
        k_cvt_x<<<dim3(KB, M / 64), 256, 0, stream>>>(x, xb, M);
        k_wtrans<<<nnz, 256, 0, stream>>>(w, wT);
        k_csc<<<1, 256, 0, stream>>>(idx_i, idx_j, colptr, colinfo, nnz);
        k_bsmm<<<(M / 256) * NBJ, 256, 0, stream>>>(xb, wT, colptr, colinfo, y, M);
    } else {
        k_bsmm_nows<<<dim3(M / 256, NBJ), 256, 0, stream>>>(x, w, idx_i, idx_j, y, nnz);
    }
}

// Round 5
// 172.829 us; speedup vs baseline: 1.1615x; 1.0414x over previous
//
#include <hip/hip_runtime.h>
#include <hip/hip_bf16.h>

typedef __bf16 bf16x8 __attribute__((ext_vector_type(8)));
typedef __bf16 bf16x4 __attribute__((ext_vector_type(4)));
typedef float f32x4 __attribute__((ext_vector_type(4)));

#define KDIM 4096   // K = 128 blocks * 32
#define NDIM 4096   // N = 128 blocks * 32
#define NBJ  128    // output block-columns
#define KB   128    // input  block-rows

// ---- fused prep: [0, nbCvt) cvt+permute x | [nbCvt, +nnz) wtrans | last: csc
__global__ __launch_bounds__(256) void k_prep(
    const float* __restrict__ x, const float* __restrict__ w,
    const int* __restrict__ idx_i, const int* __restrict__ idx_j,
    __bf16* __restrict__ xb, __bf16* __restrict__ wT,
    int* __restrict__ colptr, int* __restrict__ colinfo,
    int nnz, int M, int nbCvt) {
    __shared__ char smem[2176];
    int b = blockIdx.x, t = threadIdx.x;

    if (b < nbCvt) {
        // xb[i][m][k] = bf16(x[m][i*32+k]); 64 rows per WG
        int i  = b & (KB - 1);
        int m0 = (b >> 7) * 64;
        int q  = t & 3, r = t >> 2;
        const float* xp = x + (size_t)(m0 + r) * KDIM + i * 32 + q * 8;
        float4 u = ((const float4*)xp)[0];
        float4 v = ((const float4*)xp)[1];
        bf16x8 o;
        o[0]=(__bf16)u.x; o[1]=(__bf16)u.y; o[2]=(__bf16)u.z; o[3]=(__bf16)u.w;
        o[4]=(__bf16)v.x; o[5]=(__bf16)v.y; o[6]=(__bf16)v.z; o[7]=(__bf16)v.w;
        *(bf16x8*)(xb + ((size_t)i * M + m0 + r) * 32 + q * 8) = o;
    } else if (b < nbCvt + nnz) {
        // wT[n][c][k] = bf16(w[n][k][c])
        auto tile = (__bf16(*)[33])smem;
        int n = b - nbCvt;
        float4 v = ((const float4*)(w + (size_t)n * 1024))[t];
        int e = t * 4, k = e >> 5, c = e & 31;
        tile[k][c + 0] = (__bf16)v.x; tile[k][c + 1] = (__bf16)v.y;
        tile[k][c + 2] = (__bf16)v.z; tile[k][c + 3] = (__bf16)v.w;
        __syncthreads();
        int f = t * 4, cc = f >> 5, kk = f & 31;
        bf16x4 o;
        o[0] = tile[kk + 0][cc]; o[1] = tile[kk + 1][cc];
        o[2] = tile[kk + 2][cc]; o[3] = tile[kk + 3][cc];
        ((bf16x4*)(wT + (size_t)n * 1024))[t] = o;
    } else {
        // CSC build: colptr + packed (ib<<16)|n colinfo
        int* cnt = (int*)smem;          // [NBJ]
        int* cur = cnt + NBJ;           // [NBJ]
        if (t < NBJ) cnt[t] = 0;
        __syncthreads();
        for (int n = t; n < nnz; n += 256) atomicAdd(&cnt[idx_j[n]], 1);
        __syncthreads();
        int mycount = (t < NBJ) ? cnt[t] : 0;
        for (int off = 1; off < NBJ; off <<= 1) {
            int add = (t < NBJ && t >= off) ? cnt[t - off] : 0;
            __syncthreads();
            if (t < NBJ) cnt[t] += add;
            __syncthreads();
        }
        if (t < NBJ) {
            colptr[t + 1] = cnt[t];
            cur[t] = cnt[t] - mycount;
            if (t == 0) colptr[0] = 0;
        }
        __syncthreads();
        for (int n = t; n < nnz; n += 256) {
            int j = idx_j[n];
            int pos = atomicAdd(&cur[j], 1);
            colinfo[pos] = (idx_i[n] << 16) | n;
        }
    }
}

// ---- main kernel ------------------------------------------------------------
// 1-D grid decoded so all columns of a row-chunk share an XCD slot (linear%8).
// Branchless 2-deep load pipeline; index list broadcast via shfl (cnt<=64 path).
struct Frag { bf16x8 a0, a1, a2, a3, b0, b1; };

__global__ __launch_bounds__(256) void k_bsmm(
    const __bf16* __restrict__ xb, const __bf16* __restrict__ wT,
    const int* __restrict__ colptr, const int* __restrict__ colinfo,
    float* __restrict__ y, int M) {
    int RCH = M >> 8;
    int l = blockIdx.x;
    int rc, j;
    if ((RCH & 7) == 0) {
        int rps = RCH >> 3;
        int s = l & 7, u = l >> 3;
        rc = s * rps + (u % rps);
        j  = u / rps;
    } else {
        rc = l % RCH; j = l / RCH;
    }
    int lane = threadIdx.x & 63, wave = threadIdx.x >> 6;
    int quad = lane >> 4, l16 = lane & 15;
    int wrow = rc * 256 + wave * 64;

    int beg = colptr[j], end = colptr[j + 1];
    int cnt = end - beg;

    f32x4 acc[4][2] = {};

    if (cnt > 0) {
        size_t strideA = (size_t)M * 32;                       // elems per ib slab
        const __bf16* xbase = xb + (size_t)(wrow + l16) * 32 + quad * 8;
        const __bf16* wbase = wT + l16 * 32 + quad * 8;
        int cap = cnt - 1;

        if (cnt <= 64) {
            int einfo = colinfo[beg + (lane <= cap ? lane : cap)];
            auto fetch = [&](int p) {
                int pp = p <= cap ? p : cap;
                int ee = __shfl(einfo, pp);
                int n = ee & 0xFFFF, ib = ee >> 16;
                Frag f;
                const __bf16* xp = xbase + (size_t)ib * strideA;
                f.a0 = *(const bf16x8*)(xp);
                f.a1 = *(const bf16x8*)(xp + 16 * 32);
                f.a2 = *(const bf16x8*)(xp + 32 * 32);
                f.a3 = *(const bf16x8*)(xp + 48 * 32);
                const __bf16* wp = wbase + (size_t)n * 1024;
                f.b0 = *(const bf16x8*)(wp);
                f.b1 = *(const bf16x8*)(wp + 512);
                return f;
            };
            Frag f0 = fetch(0);
            Frag f1 = fetch(1);
            for (int p = 0; p < cnt; ++p) {
                acc[0][0] = __builtin_amdgcn_mfma_f32_16x16x32_bf16(f0.a0, f0.b0, acc[0][0], 0, 0, 0);
                acc[0][1] = __builtin_amdgcn_mfma_f32_16x16x32_bf16(f0.a0, f0.b1, acc[0][1], 0, 0, 0);
                acc[1][0] = __builtin_amdgcn_mfma_f32_16x16x32_bf16(f0.a1, f0.b0, acc[1][0], 0, 0, 0);
                acc[1][1] = __builtin_amdgcn_mfma_f32_16x16x32_bf16(f0.a1, f0.b1, acc[1][1], 0, 0, 0);
                acc[2][0] = __builtin_amdgcn_mfma_f32_16x16x32_bf16(f0.a2, f0.b0, acc[2][0], 0, 0, 0);
                acc[2][1] = __builtin_amdgcn_mfma_f32_16x16x32_bf16(f0.a2, f0.b1, acc[2][1], 0, 0, 0);
                acc[3][0] = __builtin_amdgcn_mfma_f32_16x16x32_bf16(f0.a3, f0.b0, acc[3][0], 0, 0, 0);
                acc[3][1] = __builtin_amdgcn_mfma_f32_16x16x32_bf16(f0.a3, f0.b1, acc[3][1], 0, 0, 0);
                f0 = f1;
                f1 = fetch(p + 2);
            }
        } else {
            auto fetch = [&](int p) {
                int pp = p <= cap ? p : cap;
                int ee = colinfo[beg + pp];
                int n = ee & 0xFFFF, ib = ee >> 16;
                Frag f;
                const __bf16* xp = xbase + (size_t)ib * strideA;
                f.a0 = *(const bf16x8*)(xp);
                f.a1 = *(const bf16x8*)(xp + 16 * 32);
                f.a2 = *(const bf16x8*)(xp + 32 * 32);
                f.a3 = *(const bf16x8*)(xp + 48 * 32);
                const __bf16* wp = wbase + (size_t)n * 1024;
                f.b0 = *(const bf16x8*)(wp);
                f.b1 = *(const bf16x8*)(wp + 512);
                return f;
            };
            Frag f0 = fetch(0);
            Frag f1 = fetch(1);
            for (int p = 0; p < cnt; ++p) {
                acc[0][0] = __builtin_amdgcn_mfma_f32_16x16x32_bf16(f0.a0, f0.b0, acc[0][0], 0, 0, 0);
                acc[0][1] = __builtin_amdgcn_mfma_f32_16x16x32_bf16(f0.a0, f0.b1, acc[0][1], 0, 0, 0);
                acc[1][0] = __builtin_amdgcn_mfma_f32_16x16x32_bf16(f0.a1, f0.b0, acc[1][0], 0, 0, 0);
                acc[1][1] = __builtin_amdgcn_mfma_f32_16x16x32_bf16(f0.a1, f0.b1, acc[1][1], 0, 0, 0);
                acc[2][0] = __builtin_amdgcn_mfma_f32_16x16x32_bf16(f0.a2, f0.b0, acc[2][0], 0, 0, 0);
                acc[2][1] = __builtin_amdgcn_mfma_f32_16x16x32_bf16(f0.a2, f0.b1, acc[2][1], 0, 0, 0);
                acc[3][0] = __builtin_amdgcn_mfma_f32_16x16x32_bf16(f0.a3, f0.b0, acc[3][0], 0, 0, 0);
                acc[3][1] = __builtin_amdgcn_mfma_f32_16x16x32_bf16(f0.a3, f0.b1, acc[3][1], 0, 0, 0);
                f0 = f1;
                f1 = fetch(p + 2);
            }
        }
    }

    // C/D layout: row = quad*4 + reg, col = lane&15
    #pragma unroll
    for (int r = 0; r < 4; ++r)
        #pragma unroll
        for (int ch = 0; ch < 2; ++ch)
            #pragma unroll
            for (int reg = 0; reg < 4; ++reg) {
                int row = wrow + r * 16 + quad * 4 + reg;
                int col = j * 32 + ch * 16 + l16;
                y[(size_t)row * NDIM + col] = acc[r][ch][reg];
            }
}

// ---- fallback (no workspace): fp32 reads, convert in-kernel -----------------
__global__ __launch_bounds__(256) void k_bsmm_nows(
    const float* __restrict__ x, const float* __restrict__ w,
    const int* __restrict__ idx_i, const int* __restrict__ idx_j,
    float* __restrict__ y, int nnz) {
    __shared__ int list[256];
    __shared__ int listn;
    __shared__ __bf16 tw[32][40];
    int j = blockIdx.y;
    int tid = threadIdx.x;
    int lane = tid & 63, wave = tid >> 6;
    int quad = lane >> 4, l16 = lane & 15;
    int wrow = blockIdx.x * 256 + wave * 64;

    if (tid == 0) listn = 0;
    __syncthreads();
    for (int n = tid; n < nnz; n += 256)
        if (idx_j[n] == j) { int p = atomicAdd(&listn, 1); list[p & 255] = n; }
    __syncthreads();
    int cnt = listn;

    f32x4 acc[4][2] = {};
    for (int p = 0; p < cnt; ++p) {
        int n = list[p];
        int ib = idx_i[n];
        {
            float4 v = ((const float4*)(w + (size_t)n * 1024))[tid];
            int e = tid * 4, k = e >> 5, c = e & 31;
            tw[c + 0][k] = (__bf16)v.x; tw[c + 1][k] = (__bf16)v.y;
            tw[c + 2][k] = (__bf16)v.z; tw[c + 3][k] = (__bf16)v.w;
        }
        __syncthreads();
        bf16x8 a[4];
        #pragma unroll
        for (int r = 0; r < 4; ++r) {
            const float* xp = x + (size_t)(wrow + r * 16 + l16) * KDIM + ib * 32 + quad * 8;
            float4 u = *(const float4*)(xp);
            float4 v = *(const float4*)(xp + 4);
            a[r][0] = (__bf16)u.x; a[r][1] = (__bf16)u.y; a[r][2] = (__bf16)u.z; a[r][3] = (__bf16)u.w;
            a[r][4] = (__bf16)v.x; a[r][5] = (__bf16)v.y; a[r][6] = (__bf16)v.z; a[r][7] = (__bf16)v.w;
        }
        bf16x8 b0 = *(const bf16x8*)&tw[l16][quad * 8];
        bf16x8 b1 = *(const bf16x8*)&tw[l16 + 16][quad * 8];
        #pragma unroll
        for (int r = 0; r < 4; ++r) {
            acc[r][0] = __builtin_amdgcn_mfma_f32_16x16x32_bf16(a[r], b0, acc[r][0], 0, 0, 0);
            acc[r][1] = __builtin_amdgcn_mfma_f32_16x16x32_bf16(a[r], b1, acc[r][1], 0, 0, 0);
        }
        __syncthreads();
    }

    #pragma unroll
    for (int r = 0; r < 4; ++r)
        #pragma unroll
        for (int ch = 0; ch < 2; ++ch)
            #pragma unroll
            for (int reg = 0; reg < 4; ++reg) {
                int row = wrow + r * 16 + quad * 4 + reg;
                int col = j * 32 + ch * 16 + l16;
                y[(size_t)row * NDIM + col] = acc[r][ch][reg];
            }
}

extern "C" void kernel_launch(void* const* d_in, const int* in_sizes, int n_in,
                              void* d_out, int out_size, void* d_ws, size_t ws_size,
                              hipStream_t stream) {
    const float* x     = (const float*)d_in[0];
    const float* w     = (const float*)d_in[1];
    const int*   idx_i = (const int*)d_in[2];
    const int*   idx_j = (const int*)d_in[3];
    float*       y     = (float*)d_out;

    int nnz = in_sizes[2];
    int M   = in_sizes[0] / KDIM;                   // 4096

    size_t xb_bytes = (size_t)M * KDIM * 2;         // 32 MB
    size_t wt_bytes = (size_t)nnz * 1024 * 2;
    size_t need = xb_bytes + wt_bytes + (size_t)(NBJ + 2 + nnz) * 4;

    if (ws_size >= need && (M & 255) == 0) {
        __bf16* xb      = (__bf16*)d_ws;
        __bf16* wT      = (__bf16*)((char*)d_ws + xb_bytes);
        int*    colptr  = (int*)((char*)d_ws + xb_bytes + wt_bytes);
        int*    colinfo = colptr + NBJ + 1;
        int nbCvt = KB * (M / 64);                  // 8192
        k_prep<<<nbCvt + nnz + 1, 256, 0, stream>>>(x, w, idx_i, idx_j,
                                                    xb, wT, colptr, colinfo,
                                                    nnz, M, nbCvt);
        k_bsmm<<<(M / 256) * NBJ, 256, 0, stream>>>(xb, wT, colptr, colinfo, y, M);
    } else {
        k_bsmm_nows<<<dim3(M / 256, NBJ), 256, 0, stream>>>(x, w, idx_i, idx_j, y, nnz);
    }
}